// Round 3
// baseline (181.306 us; speedup 1.0000x reference)
//
#include <hip/hip_runtime.h>

#define DD 512
#define MM 64
#define BB 16
#define NN 8192
#define KK 4
#define DP1 513
#define CAP 1024          // bucket capacity per expert (max load ~620)
#define GPE 32            // blocks per expert in pass A / pass C
#define INV_OFF 65600     // float offset of inv_norm in ws (after cnt+buckets)
#define PART_OFF 524288   // byte offset of bf16 partial buffer in ws
#define NPAIR (NN * KK)

typedef unsigned int uint;
typedef unsigned short ushort;

__device__ __forceinline__ ushort f2bf(float f) {
    uint u = __builtin_bit_cast(uint, f);
    uint r = (u + 0x7FFFu + ((u >> 16) & 1u)) >> 16;
    return (ushort)r;
}
__device__ __forceinline__ float bf2f_lo(uint packed) {
    return __builtin_bit_cast(float, packed << 16);
}
__device__ __forceinline__ float bf2f_hi(uint packed) {
    return __builtin_bit_cast(float, packed & 0xFFFF0000u);
}

// ---------------------------------------------------------------------------
// norm: inv_norm[m,b] = 1/||U[m,:,b]||  (into ws), zero loss slot
// ---------------------------------------------------------------------------
__global__ __launch_bounds__(256) void norm_kernel(
    const float* __restrict__ U, float* __restrict__ inv_norm,
    float* __restrict__ loss_slot)
{
    const int m = blockIdx.x;
    const int t = threadIdx.x;
    const float* Um = U + (long)m * DP1 * BB;
    float acc = 0.f;
    for (int idx = t; idx < DP1 * BB; idx += 256) {
        float v = Um[idx];
        acc += v * v;
    }
    __shared__ float s[256];
    s[t] = acc;
    __syncthreads();
    if (t < BB) {
        float tot = 0.f;
        #pragma unroll
        for (int j = 0; j < 16; ++j) tot += s[t + 16 * j];
        inv_norm[m * BB + t] = rsqrtf(tot);
    }
    if (m == 0 && t == 0) *loss_slot = 0.f;
}

// ---------------------------------------------------------------------------
// Counting sort of pairs by expert. ws: [0..63] counts, [64..) buckets.
// ---------------------------------------------------------------------------
__global__ __launch_bounds__(256) void build_buckets(
    const int* __restrict__ topk, int* __restrict__ ws)
{
    int* cnt = ws;
    int* bkt = ws + 64;
    __shared__ int lc[MM], lb[MM];
    const int t = threadIdx.x;
    if (t < MM) lc[t] = 0;
    __syncthreads();
    const int p = blockIdx.x * 256 + t;     // pair id = n*K + k
    const int e = topk[p];
    const int my = atomicAdd(&lc[e], 1);
    __syncthreads();
    if (t < MM) lb[t] = atomicAdd(&cnt[t], lc[t]);
    __syncthreads();
    bkt[e * CAP + lb[e] + my] = p;
}

// ---------------------------------------------------------------------------
// Pass A: per-(expert,slice), compute bf16 partial writes.
// ---------------------------------------------------------------------------
__global__ __launch_bounds__(256) void pass_writes(
    const float* __restrict__ h_sparse,
    const float* __restrict__ U,
    void* __restrict__ ws)
{
    const int e = blockIdx.x >> 5;          // / GPE
    const int g = blockIdx.x & (GPE - 1);
    const int t = threadIdx.x;
    const int lane = t & 63;
    const int pg = t >> 6;
    const float* Ug = U + (long)e * DP1 * BB;

    __shared__ float inv_s[BB];
    __shared__ int ids_s[16];

    const int* cnt = (const int*)ws;
    const int* bkt = cnt + 64;
    if (t < BB) inv_s[t] = ((const float*)ws)[INV_OFF + e * BB + t];

    const int c  = cnt[e];
    const int lo = (c * g) / GPE;
    const int hi = (c * (g + 1)) / GPE;
    const int nt = (hi - lo + 15) >> 4;
    ushort* part = (ushort*)((char*)ws + PART_OFF);

    for (int tile = 0; tile < nt; ++tile) {
        __syncthreads();
        if (t < 16) {
            const int i = lo + tile * 16 + t;
            ids_s[t] = (i < hi) ? bkt[e * CAP + i] : 0;
        }
        __syncthreads();

        // this wave's 4 pairs: h rows folded with inv_norm, in registers
        float hs[4][16];
        #pragma unroll
        for (int pp = 0; pp < 4; ++pp) {
            const int p = pg * 4 + pp;
            const bool ok = (lo + tile * 16 + p) < hi;
            const int id = ids_s[p];
            const float4* hp = (const float4*)(h_sparse + (long)id * BB);
            #pragma unroll
            for (int q = 0; q < 4; ++q) {
                float4 hv = ok ? hp[q] : make_float4(0.f, 0.f, 0.f, 0.f);
                hs[pp][4 * q + 0] = hv.x * inv_s[4 * q + 0];
                hs[pp][4 * q + 1] = hv.y * inv_s[4 * q + 1];
                hs[pp][4 * q + 2] = hv.z * inv_s[4 * q + 2];
                hs[pp][4 * q + 3] = hv.w * inv_s[4 * q + 3];
            }
        }

        float acc[4][8];
        #pragma unroll
        for (int pp = 0; pp < 4; ++pp)
            #pragma unroll
            for (int dd = 0; dd < 8; ++dd) acc[pp][dd] = 0.f;

        #pragma unroll
        for (int dd = 0; dd < 8; ++dd) {
            const int d = dd * 64 + lane;
            const float4* up = (const float4*)(Ug + (long)d * BB);
            #pragma unroll
            for (int q = 0; q < 4; ++q) {
                const float4 u = up[q];
                #pragma unroll
                for (int pp = 0; pp < 4; ++pp) {
                    acc[pp][dd] += u.x * hs[pp][4 * q + 0]
                                 + u.y * hs[pp][4 * q + 1]
                                 + u.z * hs[pp][4 * q + 2]
                                 + u.w * hs[pp][4 * q + 3];
                }
            }
        }

        #pragma unroll
        for (int pp = 0; pp < 4; ++pp) {
            const int p = pg * 4 + pp;
            if ((lo + tile * 16 + p) < hi) {
                const int id = ids_s[p];
                const int n = id >> 2, k = id & 3;
                ushort* prow = part + ((long)(k * NN + n) << 9);
                #pragma unroll
                for (int dd = 0; dd < 8; ++dd)
                    prow[dd * 64 + lane] = f2bf(acc[pp][dd]);
            }
        }
    }
}

// ---------------------------------------------------------------------------
// Pass B: writes[n,d] = sum_k partial[k][n][d]   (1 uint4 group per thread)
// ---------------------------------------------------------------------------
__global__ __launch_bounds__(256) void pass_reduce(
    const void* __restrict__ ws, float* __restrict__ out)
{
    const uint4* part4 = (const uint4*)((const char*)ws + PART_OFF);
    const int gsz = NN * DD / 8;   // uint4 groups per k
    const int gid = blockIdx.x * 256 + threadIdx.x;
    float s[8];
    #pragma unroll
    for (int j = 0; j < 8; ++j) s[j] = 0.f;
    #pragma unroll
    for (int k = 0; k < KK; ++k) {
        const uint4 v = part4[(long)k * gsz + gid];
        s[0] += bf2f_lo(v.x); s[1] += bf2f_hi(v.x);
        s[2] += bf2f_lo(v.y); s[3] += bf2f_hi(v.y);
        s[4] += bf2f_lo(v.z); s[5] += bf2f_hi(v.z);
        s[6] += bf2f_lo(v.w); s[7] += bf2f_hi(v.w);
    }
    float4* out4 = (float4*)out;
    out4[(long)gid * 2 + 0] = make_float4(s[0], s[1], s[2], s[3]);
    out4[(long)gid * 2 + 1] = make_float4(s[4], s[5], s[6], s[7]);
}

// ---------------------------------------------------------------------------
// Pass C: recon + loss, expert-centric.
// ---------------------------------------------------------------------------
__global__ __launch_bounds__(256) void pass_recon(
    const float* __restrict__ h_sparse,
    const float* __restrict__ U,
    const void* __restrict__ ws,
    float* __restrict__ out)
{
    const int e = blockIdx.x >> 5;          // / GPE
    const int g = blockIdx.x & (GPE - 1);
    const int t = threadIdx.x;
    const int pg = t >> 6;          // wave id: pairs pg*4..pg*4+3
    const int bg = (t >> 4) & 3;    // b quad
    const int dg = t & 15;          // d slice
    const float* Ug = U + (long)e * DP1 * BB;

    __shared__ float w_s[16 * DD];  // 32 KB
    __shared__ float inv_s[BB];
    __shared__ int ids_s[16];
    __shared__ float loss_s;

    const int* cnt = (const int*)ws;
    const int* bkt = cnt + 64;
    if (t < BB) inv_s[t] = ((const float*)ws)[INV_OFF + e * BB + t];
    if (t == 0) loss_s = 0.f;

    const int c  = cnt[e];
    const int lo = (c * g) / GPE;
    const int hi = (c * (g + 1)) / GPE;
    const int nt = (hi - lo + 15) >> 4;

    for (int tile = 0; tile < nt; ++tile) {
        __syncthreads();
        if (t < 16) {
            const int i = lo + tile * 16 + t;
            ids_s[t] = (i < hi) ? bkt[e * CAP + i] : 0;
        }
        __syncthreads();
        // stage 16 writes rows (float4 coalesced)
        {
            float4* w4 = (float4*)w_s;
            #pragma unroll
            for (int j = 0; j < 8; ++j) {
                const int f = t + j * 256;           // 2048 float4s
                const int row = f >> 7, col = f & 127;
                const int n = ids_s[row] >> 2;
                w4[f] = ((const float4*)(out + (long)n * DD))[col];
            }
        }
        __syncthreads();

        float acc[4][4];
        #pragma unroll
        for (int pp = 0; pp < 4; ++pp)
            #pragma unroll
            for (int x = 0; x < 4; ++x) acc[pp][x] = 0.f;

        #pragma unroll 8
        for (int j = 0; j < 32; ++j) {
            const int d = j * 16 + dg;
            const float4 u = ((const float4*)(Ug + (long)d * BB))[bg];
            #pragma unroll
            for (int pp = 0; pp < 4; ++pp) {
                const float w = w_s[(pg * 4 + pp) * DD + d];
                acc[pp][0] += w * u.x;
                acc[pp][1] += w * u.y;
                acc[pp][2] += w * u.z;
                acc[pp][3] += w * u.w;
            }
        }
        // butterfly-reduce over the 16 d-slices (low 4 lane bits)
        #pragma unroll
        for (int off = 1; off < 16; off <<= 1) {
            #pragma unroll
            for (int pp = 0; pp < 4; ++pp)
                #pragma unroll
                for (int x = 0; x < 4; ++x)
                    acc[pp][x] += __shfl_xor(acc[pp][x], off, 64);
        }
        if (dg == 0) {
            float lsum = 0.f;
            #pragma unroll
            for (int pp = 0; pp < 4; ++pp) {
                const int p = pg * 4 + pp;
                if ((lo + tile * 16 + p) < hi) {
                    const int id = ids_s[p];
                    #pragma unroll
                    for (int x = 0; x < 4; ++x) {
                        const int b = bg * 4 + x;
                        const float recon = acc[pp][x] * inv_s[b];
                        const float diff = recon - h_sparse[(long)id * BB + b];
                        lsum += diff * diff;
                    }
                }
            }
            atomicAdd(&loss_s, lsum);
        }
    }
    __syncthreads();
    if (t == 0 && loss_s != 0.f)
        atomicAdd(out + (long)NN * DD, loss_s * (1.0f / ((float)NN * KK * BB)));
}

// ---------------------------------------------------------------------------
// Fallback path (round-1 proven kernels) — used when ws is too small
// ---------------------------------------------------------------------------
__global__ __launch_bounds__(256) void dense_write_kernel(
    const float* __restrict__ h_sparse,
    const int*   __restrict__ topk,
    const float* __restrict__ U,
    const float* __restrict__ inv_norm,
    float* __restrict__ out)
{
    const int n = blockIdx.x;
    const int t = threadIdx.x;

    __shared__ float hs[KK * BB];
    __shared__ float ho[KK * BB];
    __shared__ float inv_s[KK * BB];
    __shared__ int   eidx[KK];
    __shared__ float w_s[DD];
    __shared__ float red[256];

    if (t < KK) eidx[t] = topk[n * KK + t];
    __syncthreads();
    if (t < KK * BB) {
        const int k = t / BB, b = t % BB;
        const float h  = h_sparse[(long)n * KK * BB + t];
        const float iv = inv_norm[eidx[k] * BB + b];
        ho[t]    = h;
        inv_s[t] = iv;
        hs[t]    = h * iv;
    }
    __syncthreads();

    #pragma unroll
    for (int dd = 0; dd < 2; ++dd) {
        const int d = t + dd * 256;
        float w = 0.f;
        #pragma unroll
        for (int k = 0; k < KK; ++k) {
            const float4* row = (const float4*)(U + ((long)eidx[k] * DP1 + d) * BB);
            #pragma unroll
            for (int q = 0; q < 4; ++q) {
                const float4 u4 = row[q];
                w += u4.x * hs[k * BB + 4 * q + 0];
                w += u4.y * hs[k * BB + 4 * q + 1];
                w += u4.z * hs[k * BB + 4 * q + 2];
                w += u4.w * hs[k * BB + 4 * q + 3];
            }
        }
        w_s[d] = w;
        out[(long)n * DD + d] = w;
    }
    __syncthreads();

    {
        const int pair = t & 63;
        const int k = pair >> 4, b = pair & 15;
        const int ch = t >> 6;
        const float* Ucol = U + (long)eidx[k] * DP1 * BB + b;
        float p = 0.f;
        #pragma unroll 8
        for (int d = ch * 128; d < ch * 128 + 128; ++d) {
            p += Ucol[(long)d * BB] * w_s[d];
        }
        red[t] = p;
    }
    __syncthreads();

    if (t < 64) {
        const float recon = (red[t] + red[t + 64] + red[t + 128] + red[t + 192]) * inv_s[t];
        const float diff  = recon - ho[t];
        float sq = diff * diff;
        #pragma unroll
        for (int off = 32; off > 0; off >>= 1) sq += __shfl_down(sq, off, 64);
        if (t == 0) {
            atomicAdd(out + (long)NN * DD, sq * (1.0f / ((float)NN * KK * BB)));
        }
    }
}

// ---------------------------------------------------------------------------

extern "C" void kernel_launch(void* const* d_in, const int* in_sizes, int n_in,
                              void* d_out, int out_size, void* d_ws, size_t ws_size,
                              hipStream_t stream) {
    const float* h_sparse = (const float*)d_in[0];
    const int*   topk     = (const int*)d_in[1];
    const float* U        = (const float*)d_in[2];
    float* out = (float*)d_out;

    const size_t need = (size_t)PART_OFF + (size_t)2 * KK * NN * DD; // 34,078,720 B

    if (ws_size >= need) {
        hipMemsetAsync(d_ws, 0, 64 * sizeof(int), stream);   // expert counters
        hipLaunchKernelGGL(norm_kernel, dim3(MM), dim3(256), 0, stream,
                           U, (float*)d_ws + INV_OFF, out + (long)NN * DD);
        hipLaunchKernelGGL(build_buckets, dim3(NPAIR / 256), dim3(256), 0, stream,
                           topk, (int*)d_ws);
        hipLaunchKernelGGL(pass_writes, dim3(MM * GPE), dim3(256), 0, stream,
                           h_sparse, U, d_ws);
        hipLaunchKernelGGL(pass_reduce, dim3(NN * DD / 8 / 256), dim3(256), 0, stream,
                           d_ws, out);
        hipLaunchKernelGGL(pass_recon, dim3(MM * GPE), dim3(256), 0, stream,
                           h_sparse, U, d_ws, out);
    } else {
        float* inv_norm = (float*)d_ws;
        hipLaunchKernelGGL(norm_kernel, dim3(MM), dim3(256), 0, stream,
                           U, inv_norm, out + (long)NN * DD);
        hipLaunchKernelGGL(dense_write_kernel, dim3(NN), dim3(256), 0, stream,
                           h_sparse, topk, U, inv_norm, out);
    }
}

// Round 4
// 141.499 us; speedup vs baseline: 1.2813x; 1.2813x over previous
//
#include <hip/hip_runtime.h>

#define DD 512
#define MM 64
#define BB 16
#define NN 8192
#define KK 4
#define DP1 513
#define CAP 1024
#define GPE 8
#define NPAIR (NN * KK)

// ws byte offsets (fast path)
#define CNT_B  0                     // 64 int expert counts
#define BKT_B  256                   // 64*1024 ushort pair ids
#define U_B    131328                // bf16 u[m][d][b], 1 MB
#define UT_B   1179904               // bf16 ut[m][b][d], 1 MB
#define PART_B 2228480               // bf16 part[k][n][d], 32 MB
#define WS_NEED (PART_B + (size_t)2 * KK * NN * DD)   // 35,782,912 B

typedef unsigned int uint;
typedef unsigned short ushort;
typedef __attribute__((ext_vector_type(8))) short short8;
typedef __attribute__((ext_vector_type(4))) float f32x4;

struct __align__(8) U16x4 { ushort x, y, z, w; };

__device__ __forceinline__ ushort f2bf(float f) {
    uint u = __builtin_bit_cast(uint, f);
    uint r = (u + 0x7FFFu + ((u >> 16) & 1u)) >> 16;
    return (ushort)r;
}
__device__ __forceinline__ float bf2f(ushort s) {
    return __builtin_bit_cast(float, (uint)s << 16);
}

// ---------------------------------------------------------------------------
// prep: inv_norm folded into bf16 copies of U in two layouts; zero loss slot
// ---------------------------------------------------------------------------
__global__ __launch_bounds__(256) void prep_kernel(
    const float* __restrict__ U, void* __restrict__ ws,
    float* __restrict__ loss_slot)
{
    const int m = blockIdx.x, t = threadIdx.x;
    const float* Um = U + (long)m * DP1 * BB;
    __shared__ float red[256];
    __shared__ float inv_s[BB];

    float a = 0.f;
    for (int i = t; i < DP1 * BB; i += 256) { float v = Um[i]; a += v * v; }
    red[t] = a;
    __syncthreads();
    if (t < BB) {
        float tot = 0.f;
        #pragma unroll
        for (int j = 0; j < 16; ++j) tot += red[t + 16 * j];
        inv_s[t] = rsqrtf(tot);
    }
    __syncthreads();

    ushort* ub = (ushort*)((char*)ws + U_B) + (long)m * DD * BB;
    ushort* ut = (ushort*)((char*)ws + UT_B) + (long)m * BB * DD;

    // layout 1: u[d][b] (row-major, d<512), packed 2 at a time
    for (int i = t; i < DD * BB / 2; i += 256) {
        const int e0 = 2 * i;
        const float2 v = *(const float2*)(Um + e0);
        const int b0 = e0 & 15;
        const uint pk = (uint)f2bf(v.x * inv_s[b0]) |
                        ((uint)f2bf(v.y * inv_s[b0 + 1]) << 16);
        *(uint*)(ub + e0) = pk;
    }
    // layout 2: ut[b][d]
    {
        const int b = t & 15, dg = t >> 4;
        const float iv = inv_s[b];
        for (int dd = 0; dd < 32; dd += 2) {
            const int d = dg * 32 + dd;
            const uint pk = (uint)f2bf(Um[(long)d * BB + b] * iv) |
                            ((uint)f2bf(Um[(long)(d + 1) * BB + b] * iv) << 16);
            *(uint*)(ut + (long)b * DD + d) = pk;
        }
    }
    if (m == 0 && t == 0) *loss_slot = 0.f;
}

// ---------------------------------------------------------------------------
// counting sort of (n,k) pairs by expert
// ---------------------------------------------------------------------------
__global__ __launch_bounds__(256) void build_buckets(
    const int* __restrict__ topk, void* __restrict__ ws)
{
    int* cnt = (int*)ws;
    ushort* bkt = (ushort*)((char*)ws + BKT_B);
    __shared__ int lc[MM], lb[MM];
    const int t = threadIdx.x;
    if (t < MM) lc[t] = 0;
    __syncthreads();
    const int p = blockIdx.x * 256 + t;
    const int e = topk[p];
    const int my = atomicAdd(&lc[e], 1);
    __syncthreads();
    if (t < MM) lb[t] = atomicAdd(&cnt[t], lc[t]);
    __syncthreads();
    bkt[e * CAP + lb[e] + my] = (ushort)p;
}

// ---------------------------------------------------------------------------
// Pass A (MFMA): part[k][n][d] = (Un_e hs^T) per 16-pair tile.
// mfma_f32_16x16x32_bf16: m=d, n=pair, k=b (padded 16->32 with zeros).
// ---------------------------------------------------------------------------
__global__ __launch_bounds__(256) void pass_writes_mfma(
    const float* __restrict__ h_sparse, void* __restrict__ ws)
{
    const int e = blockIdx.x >> 3, g = blockIdx.x & 7;
    const int wave = threadIdx.x >> 6, lane = threadIdx.x & 63;
    const int quad = lane >> 4, l15 = lane & 15;

    const int* cnt = (const int*)ws;
    const ushort* bkt = (const ushort*)((const char*)ws + BKT_B);
    const ushort* Ue = (const ushort*)((const char*)ws + U_B) + (long)e * DD * BB;
    ushort* part = (ushort*)((char*)ws + PART_B);

    const int c  = cnt[e];
    const int lo = (c * g) >> 3;
    const int hi = (c * (g + 1)) >> 3;

    for (int base = lo + wave * 16; base < hi; base += 64) {
        const int pidx = base + l15;
        const bool valid = pidx < hi;
        const int id = valid ? (int)bkt[e * CAP + pidx] : 0;
        const int n = id >> 2, k = id & 3;

        // B-frag: h[pair=l15-of-tile][b = quad*8+j]; quads 2,3 are the zero pad
        short8 bfrag = (short8)0;
        if (quad < 2 && valid) {
            const float4* hp = (const float4*)(h_sparse + (long)id * BB + quad * 8);
            const float4 h0 = hp[0], h1 = hp[1];
            bfrag[0] = (short)f2bf(h0.x); bfrag[1] = (short)f2bf(h0.y);
            bfrag[2] = (short)f2bf(h0.z); bfrag[3] = (short)f2bf(h0.w);
            bfrag[4] = (short)f2bf(h1.x); bfrag[5] = (short)f2bf(h1.y);
            bfrag[6] = (short)f2bf(h1.z); bfrag[7] = (short)f2bf(h1.w);
        }
        ushort* prow = part + ((long)(k * NN + n) << 9);

        #pragma unroll 4
        for (int dt = 0; dt < 32; ++dt) {
            // A-frag: Un[d = dt*16 + l15][b = quad*8+j]
            short8 afrag = (short8)0;
            if (quad < 2)
                afrag = *(const short8*)(Ue + ((long)(dt * 16 + l15) << 4) + quad * 8);
            f32x4 acc = {0.f, 0.f, 0.f, 0.f};
            acc = __builtin_amdgcn_mfma_f32_16x16x32_bf16(afrag, bfrag, acc, 0, 0, 0);
            // acc[r] = C[d = dt*16 + quad*4 + r][pair = l15]
            if (valid) {
                U16x4 st;
                st.x = f2bf(acc[0]); st.y = f2bf(acc[1]);
                st.z = f2bf(acc[2]); st.w = f2bf(acc[3]);
                *(U16x4*)(prow + dt * 16 + quad * 4) = st;
            }
        }
    }
}

// ---------------------------------------------------------------------------
// Pass C (MFMA): recon[pair][b] = sum_d P[pair][d] * Un[d][b]
// P row = sum_k part[k][n][d] (fp32), k==0 pair writes it to out[n].
// m=pair, n=b, k=d (16 chained K=32 steps). Loss accumulated per block.
// ---------------------------------------------------------------------------
__global__ __launch_bounds__(256) void pass_recon_mfma(
    const float* __restrict__ h_sparse, void* __restrict__ ws,
    float* __restrict__ out)
{
    const int e = blockIdx.x >> 3, g = blockIdx.x & 7;
    const int wave = threadIdx.x >> 6, lane = threadIdx.x & 63;
    const int quad = lane >> 4, l15 = lane & 15;
    const int t = threadIdx.x;

    const int* cnt = (const int*)ws;
    const ushort* bkt = (const ushort*)((const char*)ws + BKT_B);
    const ushort* Ute = (const ushort*)((const char*)ws + UT_B) + (long)e * BB * DD;
    const ushort* part = (const ushort*)((const char*)ws + PART_B);

    __shared__ float loss_blk;
    if (t == 0) loss_blk = 0.f;
    __syncthreads();

    const int c  = cnt[e];
    const int lo = (c * g) >> 3;
    const int hi = (c * (g + 1)) >> 3;

    float lsum = 0.f;

    for (int base = lo + wave * 16; base < hi; base += 64) {
        const int pidx = base + l15;
        const bool valid = pidx < hi;
        const int id = valid ? (int)bkt[e * CAP + pidx] : 0;
        const int n = id >> 2, k = id & 3;
        const ushort* p0 = part + ((long)n << 9);
        float* outrow = out + (long)n * DD;
        const bool writer = valid && (k == 0);

        f32x4 acc = {0.f, 0.f, 0.f, 0.f};

        #pragma unroll 4
        for (int kk = 0; kk < 16; ++kk) {
            const int doff = kk * 32 + quad * 8;
            const short8 s0 = *(const short8*)(p0 + doff);
            const short8 s1 = *(const short8*)(p0 + (long)NN * DD + doff);
            const short8 s2 = *(const short8*)(p0 + 2L * NN * DD + doff);
            const short8 s3 = *(const short8*)(p0 + 3L * NN * DD + doff);
            float w[8];
            short8 afrag;
            #pragma unroll
            for (int j = 0; j < 8; ++j) {
                w[j] = bf2f((ushort)s0[j]) + bf2f((ushort)s1[j]) +
                       bf2f((ushort)s2[j]) + bf2f((ushort)s3[j]);
                afrag[j] = (short)f2bf(w[j]);
            }
            if (writer) {
                *(float4*)(outrow + doff)     = make_float4(w[0], w[1], w[2], w[3]);
                *(float4*)(outrow + doff + 4) = make_float4(w[4], w[5], w[6], w[7]);
            }
            const short8 bfrag = *(const short8*)(Ute + (long)l15 * DD + doff);
            acc = __builtin_amdgcn_mfma_f32_16x16x32_bf16(afrag, bfrag, acc, 0, 0, 0);
        }

        // acc[r] = recon[pair = base + quad*4 + r][b = l15]
        #pragma unroll
        for (int r = 0; r < 4; ++r) {
            const int pr = base + quad * 4 + r;
            if (pr < hi) {
                const int id2 = (int)bkt[e * CAP + pr];
                const float h = h_sparse[(long)id2 * BB + l15];
                const float d = acc[r] - h;
                lsum += d * d;
            }
        }
    }

    // wave reduce then block reduce then one global atomic per block
    #pragma unroll
    for (int off = 32; off > 0; off >>= 1) lsum += __shfl_xor(lsum, off, 64);
    if (lane == 0 && lsum != 0.f) atomicAdd(&loss_blk, lsum);
    __syncthreads();
    if (t == 0 && loss_blk != 0.f)
        atomicAdd(out + (long)NN * DD, loss_blk * (1.0f / ((float)NN * KK * BB)));
}

// ---------------------------------------------------------------------------
// Fallback path (round-1 proven) — used only if ws is too small
// ---------------------------------------------------------------------------
__global__ __launch_bounds__(256) void norm_kernel(
    const float* __restrict__ U, float* __restrict__ inv_norm,
    float* __restrict__ loss_slot)
{
    const int m = blockIdx.x;
    const int t = threadIdx.x;
    const float* Um = U + (long)m * DP1 * BB;
    float acc = 0.f;
    for (int idx = t; idx < DP1 * BB; idx += 256) {
        float v = Um[idx];
        acc += v * v;
    }
    __shared__ float s[256];
    s[t] = acc;
    __syncthreads();
    if (t < BB) {
        float tot = 0.f;
        #pragma unroll
        for (int j = 0; j < 16; ++j) tot += s[t + 16 * j];
        inv_norm[m * BB + t] = rsqrtf(tot);
    }
    if (m == 0 && t == 0) *loss_slot = 0.f;
}

__global__ __launch_bounds__(256) void dense_write_kernel(
    const float* __restrict__ h_sparse,
    const int*   __restrict__ topk,
    const float* __restrict__ U,
    const float* __restrict__ inv_norm,
    float* __restrict__ out)
{
    const int n = blockIdx.x;
    const int t = threadIdx.x;

    __shared__ float hs[KK * BB];
    __shared__ float ho[KK * BB];
    __shared__ float inv_s[KK * BB];
    __shared__ int   eidx[KK];
    __shared__ float w_s[DD];
    __shared__ float red[256];

    if (t < KK) eidx[t] = topk[n * KK + t];
    __syncthreads();
    if (t < KK * BB) {
        const int k = t / BB, b = t % BB;
        const float h  = h_sparse[(long)n * KK * BB + t];
        const float iv = inv_norm[eidx[k] * BB + b];
        ho[t]    = h;
        inv_s[t] = iv;
        hs[t]    = h * iv;
    }
    __syncthreads();

    #pragma unroll
    for (int dd = 0; dd < 2; ++dd) {
        const int d = t + dd * 256;
        float w = 0.f;
        #pragma unroll
        for (int k = 0; k < KK; ++k) {
            const float4* row = (const float4*)(U + ((long)eidx[k] * DP1 + d) * BB);
            #pragma unroll
            for (int q = 0; q < 4; ++q) {
                const float4 u4 = row[q];
                w += u4.x * hs[k * BB + 4 * q + 0];
                w += u4.y * hs[k * BB + 4 * q + 1];
                w += u4.z * hs[k * BB + 4 * q + 2];
                w += u4.w * hs[k * BB + 4 * q + 3];
            }
        }
        w_s[d] = w;
        out[(long)n * DD + d] = w;
    }
    __syncthreads();

    {
        const int pair = t & 63;
        const int k = pair >> 4, b = pair & 15;
        const int ch = t >> 6;
        const float* Ucol = U + (long)eidx[k] * DP1 * BB + b;
        float p = 0.f;
        #pragma unroll 8
        for (int d = ch * 128; d < ch * 128 + 128; ++d) {
            p += Ucol[(long)d * BB] * w_s[d];
        }
        red[t] = p;
    }
    __syncthreads();

    if (t < 64) {
        const float recon = (red[t] + red[t + 64] + red[t + 128] + red[t + 192]) * inv_s[t];
        const float diff  = recon - ho[t];
        float sq = diff * diff;
        #pragma unroll
        for (int off = 32; off > 0; off >>= 1) sq += __shfl_down(sq, off, 64);
        if (t == 0) {
            atomicAdd(out + (long)NN * DD, sq * (1.0f / ((float)NN * KK * BB)));
        }
    }
}

// ---------------------------------------------------------------------------

extern "C" void kernel_launch(void* const* d_in, const int* in_sizes, int n_in,
                              void* d_out, int out_size, void* d_ws, size_t ws_size,
                              hipStream_t stream) {
    const float* h_sparse = (const float*)d_in[0];
    const int*   topk     = (const int*)d_in[1];
    const float* U        = (const float*)d_in[2];
    float* out = (float*)d_out;

    if (ws_size >= WS_NEED) {
        hipMemsetAsync(d_ws, 0, 256, stream);   // expert counters
        hipLaunchKernelGGL(prep_kernel, dim3(MM), dim3(256), 0, stream,
                           U, d_ws, out + (long)NN * DD);
        hipLaunchKernelGGL(build_buckets, dim3(NPAIR / 256), dim3(256), 0, stream,
                           topk, d_ws);
        hipLaunchKernelGGL(pass_writes_mfma, dim3(MM * GPE), dim3(256), 0, stream,
                           h_sparse, d_ws);
        hipLaunchKernelGGL(pass_recon_mfma, dim3(MM * GPE), dim3(256), 0, stream,
                           h_sparse, d_ws, out);
    } else {
        float* inv_norm = (float*)d_ws;
        hipLaunchKernelGGL(norm_kernel, dim3(MM), dim3(256), 0, stream,
                           U, inv_norm, out + (long)NN * DD);
        hipLaunchKernelGGL(dense_write_kernel, dim3(NN), dim3(256), 0, stream,
                           h_sparse, topk, U, inv_norm, out);
    }
}

// Round 5
// 136.674 us; speedup vs baseline: 1.3266x; 1.0353x over previous
//
#include <hip/hip_runtime.h>

#define DD 512
#define MM 64
#define BB 16
#define NN 8192
#define KK 4
#define DP1 513
#define CAP 1024
#define GPE 8
#define NPAIR (NN * KK)

// ws byte offsets (fast path)
#define CNT_B  0                      // 64 int expert counts (256 B)
#define BKT_B  256                    // 64*1024 ushort pair ids (128 KB)
#define INV_B  131328                 // 1024 float inv_norm (4 KB)
#define U_B    135424                 // bf16 u[m][d][b], 1 MB
#define UT_B   1184000                // bf16 ut[m][b][d], 1 MB
#define WBF_B  2232576                // bf16 w[n][d], 8 MB
#define PART_B 10621184               // bf16 part[k][n][d], 32 MB
#define WS_NEED 44175616

typedef unsigned int uint;
typedef unsigned short ushort;
typedef __attribute__((ext_vector_type(8))) short short8;
typedef __attribute__((ext_vector_type(4))) float f32x4;

struct __align__(8) U16x4 { ushort x, y, z, w; };

__device__ __forceinline__ ushort f2bf(float f) {
    uint u = __builtin_bit_cast(uint, f);
    uint r = (u + 0x7FFFu + ((u >> 16) & 1u)) >> 16;
    return (ushort)r;
}
__device__ __forceinline__ float bf2f(ushort s) {
    return __builtin_bit_cast(float, (uint)s << 16);
}

// ---------------------------------------------------------------------------
// K1 norm: inv_norm[m,b] -> ws; zero loss slot
// ---------------------------------------------------------------------------
__global__ __launch_bounds__(256) void norm_kernel(
    const float* __restrict__ U, float* __restrict__ inv_norm,
    float* __restrict__ loss_slot)
{
    const int m = blockIdx.x, t = threadIdx.x;
    const float* Um = U + (long)m * DP1 * BB;
    float acc = 0.f;
    for (int idx = t; idx < DP1 * BB; idx += 256) {
        float v = Um[idx];
        acc += v * v;
    }
    __shared__ float s[256];
    s[t] = acc;
    __syncthreads();
    if (t < BB) {
        float tot = 0.f;
        #pragma unroll
        for (int j = 0; j < 16; ++j) tot += s[t + 16 * j];
        inv_norm[m * BB + t] = rsqrtf(tot);
    }
    if (m == 0 && t == 0) *loss_slot = 0.f;
}

// ---------------------------------------------------------------------------
// K2 pack: bf16 u[m][d][b] and ut[m][b][d] (LDS transpose), 4 blocks/expert
// ---------------------------------------------------------------------------
__global__ __launch_bounds__(256) void pack_kernel(
    const float* __restrict__ U, void* __restrict__ ws)
{
    const int m = blockIdx.x >> 2, sl = blockIdx.x & 3;   // d-slice of 128
    const int t = threadIdx.x;
    const float* Um = U + (long)m * DP1 * BB + (long)sl * 128 * BB;
    const float* invp = (const float*)((const char*)ws + INV_B) + m * BB;
    ushort* ub = (ushort*)((char*)ws + U_B) + (long)m * DD * BB + sl * 128 * BB;
    ushort* ut = (ushort*)((char*)ws + UT_B) + (long)m * BB * DD + sl * 128;

    __shared__ float inv_s[BB];
    __shared__ ushort tr[BB][136];   // [b][d_local], padded row for banks/align

    if (t < BB) inv_s[t] = invp[t];
    __syncthreads();

    #pragma unroll
    for (int iter = 0; iter < 4; ++iter) {
        const int i = t + iter * 256;        // pair-of-elements index, 0..1023
        const int e0 = 2 * i;                // element index, 0..2047
        const int dl = e0 >> 4, b0 = e0 & 15;
        const float2 v = *(const float2*)(Um + e0);
        const ushort bv0 = f2bf(v.x * inv_s[b0]);
        const ushort bv1 = f2bf(v.y * inv_s[b0 + 1]);
        *(uint*)(ub + e0) = (uint)bv0 | ((uint)bv1 << 16);
        tr[b0][dl] = bv0;
        tr[b0 + 1][dl] = bv1;
    }
    __syncthreads();

    // write ut rows: thread t -> b = t>>4, d_off = (t&15)*8 (16B store)
    {
        const int b = t >> 4, doff = (t & 15) * 8;
        const uint4 val = *(const uint4*)&tr[b][doff];
        *(uint4*)(ut + (long)b * DD + doff) = val;
    }
}

// ---------------------------------------------------------------------------
// K3: counting sort of (n,k) pairs by expert
// ---------------------------------------------------------------------------
__global__ __launch_bounds__(256) void build_buckets(
    const int* __restrict__ topk, void* __restrict__ ws)
{
    int* cnt = (int*)ws;
    ushort* bkt = (ushort*)((char*)ws + BKT_B);
    __shared__ int lc[MM], lb[MM];
    const int t = threadIdx.x;
    if (t < MM) lc[t] = 0;
    __syncthreads();
    const int p = blockIdx.x * 256 + t;
    const int e = topk[p];
    const int my = atomicAdd(&lc[e], 1);
    __syncthreads();
    if (t < MM) lb[t] = atomicAdd(&cnt[t], lc[t]);
    __syncthreads();
    bkt[e * CAP + lb[e] + my] = (ushort)p;
}

// ---------------------------------------------------------------------------
// K4 (MFMA): part[k][n][d] = Un_e * h^T per 16-pair tile (K=16 padded to 32)
// ---------------------------------------------------------------------------
__global__ __launch_bounds__(256) void pass_writes_mfma(
    const float* __restrict__ h_sparse, void* __restrict__ ws)
{
    const int e = blockIdx.x >> 3, g = blockIdx.x & 7;
    const int wave = threadIdx.x >> 6, lane = threadIdx.x & 63;
    const int quad = lane >> 4, l15 = lane & 15;

    const int* cnt = (const int*)ws;
    const ushort* bkt = (const ushort*)((const char*)ws + BKT_B);
    const ushort* Ue = (const ushort*)((const char*)ws + U_B) + (long)e * DD * BB;
    ushort* part = (ushort*)((char*)ws + PART_B);

    const int c  = cnt[e];
    const int lo = (c * g) >> 3;
    const int hi = (c * (g + 1)) >> 3;

    for (int base = lo + wave * 16; base < hi; base += 64) {
        const int pidx = base + l15;
        const bool valid = pidx < hi;
        const int id = valid ? (int)bkt[e * CAP + pidx] : 0;
        const int n = id >> 2, k = id & 3;

        // B-frag: h[pair=l15][b = quad*8+j]; quads 2,3 are the K zero-pad
        short8 bfrag = (short8)0;
        if (quad < 2 && valid) {
            const float4* hp = (const float4*)(h_sparse + (long)id * BB + quad * 8);
            const float4 h0 = hp[0], h1 = hp[1];
            bfrag[0] = (short)f2bf(h0.x); bfrag[1] = (short)f2bf(h0.y);
            bfrag[2] = (short)f2bf(h0.z); bfrag[3] = (short)f2bf(h0.w);
            bfrag[4] = (short)f2bf(h1.x); bfrag[5] = (short)f2bf(h1.y);
            bfrag[6] = (short)f2bf(h1.z); bfrag[7] = (short)f2bf(h1.w);
        }
        ushort* prow = part + ((long)(k * NN + n) << 9);

        #pragma unroll 4
        for (int dt = 0; dt < 32; ++dt) {
            short8 afrag = (short8)0;
            if (quad < 2)
                afrag = *(const short8*)(Ue + ((long)(dt * 16 + l15) << 4) + quad * 8);
            f32x4 acc = {0.f, 0.f, 0.f, 0.f};
            acc = __builtin_amdgcn_mfma_f32_16x16x32_bf16(afrag, bfrag, acc, 0, 0, 0);
            if (valid) {
                U16x4 st;
                st.x = f2bf(acc[0]); st.y = f2bf(acc[1]);
                st.z = f2bf(acc[2]); st.w = f2bf(acc[3]);
                *(U16x4*)(prow + dt * 16 + quad * 4) = st;
            }
        }
    }
}

// ---------------------------------------------------------------------------
// K5: w[n][d] = sum_k part[k][n][d]; write fp32 out + bf16 wbf (coalesced)
// ---------------------------------------------------------------------------
__global__ __launch_bounds__(256) void reduce_w(
    void* __restrict__ ws, float* __restrict__ out)
{
    const uint4* part4 = (const uint4*)((const char*)ws + PART_B);
    uint4* wbf4 = (uint4*)((char*)ws + WBF_B);
    const int gsz = NN * DD / 8;
    const int gid = blockIdx.x * 256 + threadIdx.x;

    const uint4 v0 = part4[gid];
    const uint4 v1 = part4[(long)gsz + gid];
    const uint4 v2 = part4[2L * gsz + gid];
    const uint4 v3 = part4[3L * gsz + gid];

    float s[8];
    s[0] = bf2f((ushort)v0.x) + bf2f((ushort)v1.x) + bf2f((ushort)v2.x) + bf2f((ushort)v3.x);
    s[1] = bf2f((ushort)(v0.x >> 16)) + bf2f((ushort)(v1.x >> 16)) + bf2f((ushort)(v2.x >> 16)) + bf2f((ushort)(v3.x >> 16));
    s[2] = bf2f((ushort)v0.y) + bf2f((ushort)v1.y) + bf2f((ushort)v2.y) + bf2f((ushort)v3.y);
    s[3] = bf2f((ushort)(v0.y >> 16)) + bf2f((ushort)(v1.y >> 16)) + bf2f((ushort)(v2.y >> 16)) + bf2f((ushort)(v3.y >> 16));
    s[4] = bf2f((ushort)v0.z) + bf2f((ushort)v1.z) + bf2f((ushort)v2.z) + bf2f((ushort)v3.z);
    s[5] = bf2f((ushort)(v0.z >> 16)) + bf2f((ushort)(v1.z >> 16)) + bf2f((ushort)(v2.z >> 16)) + bf2f((ushort)(v3.z >> 16));
    s[6] = bf2f((ushort)v0.w) + bf2f((ushort)v1.w) + bf2f((ushort)v2.w) + bf2f((ushort)v3.w);
    s[7] = bf2f((ushort)(v0.w >> 16)) + bf2f((ushort)(v1.w >> 16)) + bf2f((ushort)(v2.w >> 16)) + bf2f((ushort)(v3.w >> 16));

    float4* out4 = (float4*)out;
    out4[(long)gid * 2 + 0] = make_float4(s[0], s[1], s[2], s[3]);
    out4[(long)gid * 2 + 1] = make_float4(s[4], s[5], s[6], s[7]);

    uint4 pk;
    pk.x = (uint)f2bf(s[0]) | ((uint)f2bf(s[1]) << 16);
    pk.y = (uint)f2bf(s[2]) | ((uint)f2bf(s[3]) << 16);
    pk.z = (uint)f2bf(s[4]) | ((uint)f2bf(s[5]) << 16);
    pk.w = (uint)f2bf(s[6]) | ((uint)f2bf(s[7]) << 16);
    wbf4[gid] = pk;
}

// ---------------------------------------------------------------------------
// K6 (MFMA): recon[pair][b] = sum_d w[n][d]*Un[d][b]; loss only
// ---------------------------------------------------------------------------
__global__ __launch_bounds__(256) void pass_recon_mfma(
    const float* __restrict__ h_sparse, void* __restrict__ ws,
    float* __restrict__ out)
{
    const int e = blockIdx.x >> 3, g = blockIdx.x & 7;
    const int wave = threadIdx.x >> 6, lane = threadIdx.x & 63;
    const int quad = lane >> 4, l15 = lane & 15;
    const int t = threadIdx.x;

    const int* cnt = (const int*)ws;
    const ushort* bkt = (const ushort*)((const char*)ws + BKT_B);
    const ushort* Ute = (const ushort*)((const char*)ws + UT_B) + (long)e * BB * DD;
    const ushort* wbf = (const ushort*)((const char*)ws + WBF_B);

    __shared__ float loss_blk;
    if (t == 0) loss_blk = 0.f;
    __syncthreads();

    const int c  = cnt[e];
    const int lo = (c * g) >> 3;
    const int hi = (c * (g + 1)) >> 3;

    float lsum = 0.f;

    for (int base = lo + wave * 16; base < hi; base += 64) {
        const int pidx = base + l15;
        const bool valid = pidx < hi;
        const int id = valid ? (int)bkt[e * CAP + pidx] : 0;
        const int n = id >> 2;
        const ushort* wrow = wbf + ((long)n << 9);

        f32x4 acc = {0.f, 0.f, 0.f, 0.f};

        #pragma unroll 4
        for (int kk = 0; kk < 16; ++kk) {
            const int doff = kk * 32 + quad * 8;
            const short8 afrag = *(const short8*)(wrow + doff);
            const short8 bfrag = *(const short8*)(Ute + (long)l15 * DD + doff);
            acc = __builtin_amdgcn_mfma_f32_16x16x32_bf16(afrag, bfrag, acc, 0, 0, 0);
        }

        // acc[r] = recon[pair = base + quad*4 + r][b = l15]
        #pragma unroll
        for (int r = 0; r < 4; ++r) {
            const int pr = base + quad * 4 + r;
            if (pr < hi) {
                const int id2 = (int)bkt[e * CAP + pr];
                const float h = h_sparse[(long)id2 * BB + l15];
                const float d = acc[r] - h;
                lsum += d * d;
            }
        }
    }

    #pragma unroll
    for (int off = 32; off > 0; off >>= 1) lsum += __shfl_xor(lsum, off, 64);
    if (lane == 0 && lsum != 0.f) atomicAdd(&loss_blk, lsum);
    __syncthreads();
    if (t == 0 && loss_blk != 0.f)
        atomicAdd(out + (long)NN * DD, loss_blk * (1.0f / ((float)NN * KK * BB)));
}

// ---------------------------------------------------------------------------
// Fallback path (round-1 proven) — used only if ws is too small
// ---------------------------------------------------------------------------
__global__ __launch_bounds__(256) void dense_write_kernel(
    const float* __restrict__ h_sparse,
    const int*   __restrict__ topk,
    const float* __restrict__ U,
    const float* __restrict__ inv_norm,
    float* __restrict__ out)
{
    const int n = blockIdx.x;
    const int t = threadIdx.x;

    __shared__ float hs[KK * BB];
    __shared__ float ho[KK * BB];
    __shared__ float inv_s[KK * BB];
    __shared__ int   eidx[KK];
    __shared__ float w_s[DD];
    __shared__ float red[256];

    if (t < KK) eidx[t] = topk[n * KK + t];
    __syncthreads();
    if (t < KK * BB) {
        const int k = t / BB, b = t % BB;
        const float h  = h_sparse[(long)n * KK * BB + t];
        const float iv = inv_norm[eidx[k] * BB + b];
        ho[t]    = h;
        inv_s[t] = iv;
        hs[t]    = h * iv;
    }
    __syncthreads();

    #pragma unroll
    for (int dd = 0; dd < 2; ++dd) {
        const int d = t + dd * 256;
        float w = 0.f;
        #pragma unroll
        for (int k = 0; k < KK; ++k) {
            const float4* row = (const float4*)(U + ((long)eidx[k] * DP1 + d) * BB);
            #pragma unroll
            for (int q = 0; q < 4; ++q) {
                const float4 u4 = row[q];
                w += u4.x * hs[k * BB + 4 * q + 0];
                w += u4.y * hs[k * BB + 4 * q + 1];
                w += u4.z * hs[k * BB + 4 * q + 2];
                w += u4.w * hs[k * BB + 4 * q + 3];
            }
        }
        w_s[d] = w;
        out[(long)n * DD + d] = w;
    }
    __syncthreads();

    {
        const int pair = t & 63;
        const int k = pair >> 4, b = pair & 15;
        const int ch = t >> 6;
        const float* Ucol = U + (long)eidx[k] * DP1 * BB + b;
        float p = 0.f;
        #pragma unroll 8
        for (int d = ch * 128; d < ch * 128 + 128; ++d) {
            p += Ucol[(long)d * BB] * w_s[d];
        }
        red[t] = p;
    }
    __syncthreads();

    if (t < 64) {
        const float recon = (red[t] + red[t + 64] + red[t + 128] + red[t + 192]) * inv_s[t];
        const float diff  = recon - ho[t];
        float sq = diff * diff;
        #pragma unroll
        for (int off = 32; off > 0; off >>= 1) sq += __shfl_down(sq, off, 64);
        if (t == 0) {
            atomicAdd(out + (long)NN * DD, sq * (1.0f / ((float)NN * KK * BB)));
        }
    }
}

// ---------------------------------------------------------------------------

extern "C" void kernel_launch(void* const* d_in, const int* in_sizes, int n_in,
                              void* d_out, int out_size, void* d_ws, size_t ws_size,
                              hipStream_t stream) {
    const float* h_sparse = (const float*)d_in[0];
    const int*   topk     = (const int*)d_in[1];
    const float* U        = (const float*)d_in[2];
    float* out = (float*)d_out;

    if (ws_size >= (size_t)WS_NEED) {
        hipMemsetAsync(d_ws, 0, 256, stream);   // expert counters
        hipLaunchKernelGGL(norm_kernel, dim3(MM), dim3(256), 0, stream,
                           U, (float*)((char*)d_ws + INV_B), out + (long)NN * DD);
        hipLaunchKernelGGL(pack_kernel, dim3(MM * 4), dim3(256), 0, stream,
                           U, d_ws);
        hipLaunchKernelGGL(build_buckets, dim3(NPAIR / 256), dim3(256), 0, stream,
                           topk, d_ws);
        hipLaunchKernelGGL(pass_writes_mfma, dim3(MM * GPE), dim3(256), 0, stream,
                           h_sparse, d_ws);
        hipLaunchKernelGGL(reduce_w, dim3(NN * DD / 8 / 256), dim3(256), 0, stream,
                           d_ws, out);
        hipLaunchKernelGGL(pass_recon_mfma, dim3(MM * GPE), dim3(256), 0, stream,
                           h_sparse, d_ws, out);
    } else {
        float* inv_norm = (float*)d_ws;
        hipLaunchKernelGGL(norm_kernel, dim3(MM), dim3(256), 0, stream,
                           U, inv_norm, out + (long)NN * DD);
        hipLaunchKernelGGL(dense_write_kernel, dim3(NN), dim3(256), 0, stream,
                           h_sparse, topk, U, inv_norm, out);
    }
}

// Round 6
// 127.192 us; speedup vs baseline: 1.4254x; 1.0745x over previous
//
#include <hip/hip_runtime.h>

#define DD 512
#define MM 64
#define BB 16
#define NN 8192
#define KK 4
#define DP1 513
#define CAP 1024
#define GPE 8
#define NPAIR (NN * KK)

// ws byte offsets (fast path)
#define CNT_B  0                      // 64 int expert counts (256 B)
#define BKT_B  256                    // 64*1024 ushort pair ids (128 KB)
#define U_B    135424                 // bf16 u[m][d][b], 1 MB
#define UT_B   1184000                // bf16 ut[m][b][d], 1 MB
#define WBF_B  2232576                // bf16 w[n][d], 8 MB
#define PART_B 10621184               // bf16 part[k][n][d], 32 MB
#define WS_NEED 44175616

typedef unsigned int uint;
typedef unsigned short ushort;
typedef __attribute__((ext_vector_type(8))) short short8;
typedef __attribute__((ext_vector_type(4))) float f32x4;

__device__ __forceinline__ ushort f2bf(float f) {
    uint u = __builtin_bit_cast(uint, f);
    uint r = (u + 0x7FFFu + ((u >> 16) & 1u)) >> 16;
    return (ushort)r;
}
__device__ __forceinline__ float bf2f(ushort s) {
    return __builtin_bit_cast(float, (uint)s << 16);
}

// ---------------------------------------------------------------------------
// K1 prep: norms + bf16 u[m][d][b] + bf16 ut[m][b][d] (LDS transpose), 1 blk/expert
// ---------------------------------------------------------------------------
__global__ __launch_bounds__(256) void prep_kernel(
    const float* __restrict__ U, void* __restrict__ ws,
    float* __restrict__ loss_slot)
{
    const int m = blockIdx.x, t = threadIdx.x;
    const float* Um = U + (long)m * DP1 * BB;

    __shared__ float red[256];
    __shared__ float inv_s[BB];
    __shared__ ushort tr[BB][DD + 8];   // 16.6 KB, +8 pad

    // --- column norms over all D+1 rows ---
    float a = 0.f;
    for (int i = t; i < DP1 * BB; i += 256) { float v = Um[i]; a += v * v; }
    red[t] = a;
    __syncthreads();
    if (t < BB) {
        float tot = 0.f;
        #pragma unroll
        for (int j = 0; j < 16; ++j) tot += red[t + 16 * j];
        inv_s[t] = rsqrtf(tot);
    }
    __syncthreads();

    ushort* ub = (ushort*)((char*)ws + U_B) + (long)m * DD * BB;
    ushort* ut = (ushort*)((char*)ws + UT_B) + (long)m * BB * DD;

    // --- fold + emit u[d][b], stash transpose in LDS ---
    #pragma unroll
    for (int iter = 0; iter < 16; ++iter) {
        const int i = t + iter * 256;        // 0..4095 (pairs of elements)
        const int e0 = 2 * i;                // 0..8190, d = e0>>4 < 512
        const int d = e0 >> 4, b0 = e0 & 15;
        const float2 v = *(const float2*)(Um + e0);
        const ushort bv0 = f2bf(v.x * inv_s[b0]);
        const ushort bv1 = f2bf(v.y * inv_s[b0 + 1]);
        *(uint*)(ub + e0) = (uint)bv0 | ((uint)bv1 << 16);
        tr[b0][d] = bv0;
        tr[b0 + 1][d] = bv1;
    }
    __syncthreads();

    // --- write ut rows coalesced: thread t -> b = t>>4, 4x 16B stores ---
    {
        const int b = t >> 4, base = (t & 15) * 32;
        #pragma unroll
        for (int j = 0; j < 4; ++j) {
            const int doff = base + j * 8;
            uint4 val;
            val.x = (uint)tr[b][doff + 0] | ((uint)tr[b][doff + 1] << 16);
            val.y = (uint)tr[b][doff + 2] | ((uint)tr[b][doff + 3] << 16);
            val.z = (uint)tr[b][doff + 4] | ((uint)tr[b][doff + 5] << 16);
            val.w = (uint)tr[b][doff + 6] | ((uint)tr[b][doff + 7] << 16);
            *(uint4*)(ut + (long)b * DD + doff) = val;
        }
    }
    if (m == 0 && t == 0) *loss_slot = 0.f;
}

// ---------------------------------------------------------------------------
// K2: counting sort of (n,k) pairs by expert
// ---------------------------------------------------------------------------
__global__ __launch_bounds__(256) void build_buckets(
    const int* __restrict__ topk, void* __restrict__ ws)
{
    int* cnt = (int*)ws;
    ushort* bkt = (ushort*)((char*)ws + BKT_B);
    __shared__ int lc[MM], lb[MM];
    const int t = threadIdx.x;
    if (t < MM) lc[t] = 0;
    __syncthreads();
    const int p = blockIdx.x * 256 + t;
    const int e = topk[p];
    const int my = atomicAdd(&lc[e], 1);
    __syncthreads();
    if (t < MM) lb[t] = atomicAdd(&cnt[t], lc[t]);
    __syncthreads();
    bkt[e * CAP + lb[e] + my] = (ushort)p;
}

// ---------------------------------------------------------------------------
// K3 (MFMA): part[k][n][d] = Un_e * h^T per 16-pair tile (K=16 padded to 32).
// Stores: dt processed in pairs + quad shfl-exchange -> 16B/lane stores,
// 64 B contiguous per pair-row per store instruction.
// ---------------------------------------------------------------------------
__global__ __launch_bounds__(256) void pass_writes_mfma(
    const float* __restrict__ h_sparse, void* __restrict__ ws)
{
    const int e = blockIdx.x >> 3, g = blockIdx.x & 7;
    const int wave = threadIdx.x >> 6, lane = threadIdx.x & 63;
    const int quad = lane >> 4, l15 = lane & 15;

    const int* cnt = (const int*)ws;
    const ushort* bkt = (const ushort*)((const char*)ws + BKT_B);
    const ushort* Ue = (const ushort*)((const char*)ws + U_B) + (long)e * DD * BB;
    ushort* part = (ushort*)((char*)ws + PART_B);

    const int c  = cnt[e];
    const int lo = (c * g) >> 3;
    const int hi = (c * (g + 1)) >> 3;

    for (int base = lo + wave * 16; base < hi; base += 64) {
        const int pidx = base + l15;
        const bool valid = pidx < hi;
        const int id = valid ? (int)bkt[e * CAP + pidx] : 0;
        const int n = id >> 2, k = id & 3;

        // B-frag: h[pair=l15][b = quad*8+j]; quads 2,3 are the K zero-pad
        short8 bfrag = (short8)0;
        if (quad < 2 && valid) {
            const float4* hp = (const float4*)(h_sparse + (long)id * BB + quad * 8);
            const float4 h0 = hp[0], h1 = hp[1];
            bfrag[0] = (short)f2bf(h0.x); bfrag[1] = (short)f2bf(h0.y);
            bfrag[2] = (short)f2bf(h0.z); bfrag[3] = (short)f2bf(h0.w);
            bfrag[4] = (short)f2bf(h1.x); bfrag[5] = (short)f2bf(h1.y);
            bfrag[6] = (short)f2bf(h1.z); bfrag[7] = (short)f2bf(h1.w);
        }
        ushort* prow = part + ((long)(k * NN + n) << 9);

        #pragma unroll 2
        for (int dt = 0; dt < 32; dt += 2) {
            short8 a0 = (short8)0, a1 = (short8)0;
            if (quad < 2) {
                a0 = *(const short8*)(Ue + ((long)(dt * 16 + l15) << 4) + quad * 8);
                a1 = *(const short8*)(Ue + ((long)((dt + 1) * 16 + l15) << 4) + quad * 8);
            }
            f32x4 z = {0.f, 0.f, 0.f, 0.f};
            f32x4 c0 = __builtin_amdgcn_mfma_f32_16x16x32_bf16(a0, bfrag, z, 0, 0, 0);
            f32x4 c1 = __builtin_amdgcn_mfma_f32_16x16x32_bf16(a1, bfrag, z, 0, 0, 0);

            // pack each acc to 8B (4 bf16)
            uint p0x = (uint)f2bf(c0[0]) | ((uint)f2bf(c0[1]) << 16);
            uint p0y = (uint)f2bf(c0[2]) | ((uint)f2bf(c0[3]) << 16);
            uint p1x = (uint)f2bf(c1[0]) | ((uint)f2bf(c1[1]) << 16);
            uint p1y = (uint)f2bf(c1[2]) | ((uint)f2bf(c1[3]) << 16);
            // quad exchange (0<->1, 2<->3): same l15, same validity
            uint q0x = __shfl_xor((int)p0x, 16, 64);
            uint q0y = __shfl_xor((int)p0y, 16, 64);
            uint q1x = __shfl_xor((int)p1x, 16, 64);
            uint q1y = __shfl_xor((int)p1y, 16, 64);

            if (valid) {
                uint4 st;
                int sdt;
                if ((quad & 1) == 0) {          // store dt: own rows low, partner high
                    st.x = p0x; st.y = p0y; st.z = q0x; st.w = q0y;
                    sdt = dt;
                } else {                        // store dt+1: partner low, own high
                    st.x = q1x; st.y = q1y; st.z = p1x; st.w = p1y;
                    sdt = dt + 1;
                }
                const int srow = (quad & 2) ? 8 : 0;
                *(uint4*)(prow + sdt * 16 + srow) = st;
            }
        }
    }
}

// ---------------------------------------------------------------------------
// K4: w[n][d] = sum_k part[k][n][d]; write fp32 out + bf16 wbf (coalesced)
// ---------------------------------------------------------------------------
__global__ __launch_bounds__(256) void reduce_w(
    void* __restrict__ ws, float* __restrict__ out)
{
    const uint4* part4 = (const uint4*)((const char*)ws + PART_B);
    uint4* wbf4 = (uint4*)((char*)ws + WBF_B);
    const int gsz = NN * DD / 8;
    const int gid = blockIdx.x * 256 + threadIdx.x;

    const uint4 v0 = part4[gid];
    const uint4 v1 = part4[(long)gsz + gid];
    const uint4 v2 = part4[2L * gsz + gid];
    const uint4 v3 = part4[3L * gsz + gid];

    float s[8];
    s[0] = bf2f((ushort)v0.x) + bf2f((ushort)v1.x) + bf2f((ushort)v2.x) + bf2f((ushort)v3.x);
    s[1] = bf2f((ushort)(v0.x >> 16)) + bf2f((ushort)(v1.x >> 16)) + bf2f((ushort)(v2.x >> 16)) + bf2f((ushort)(v3.x >> 16));
    s[2] = bf2f((ushort)v0.y) + bf2f((ushort)v1.y) + bf2f((ushort)v2.y) + bf2f((ushort)v3.y);
    s[3] = bf2f((ushort)(v0.y >> 16)) + bf2f((ushort)(v1.y >> 16)) + bf2f((ushort)(v2.y >> 16)) + bf2f((ushort)(v3.y >> 16));
    s[4] = bf2f((ushort)v0.z) + bf2f((ushort)v1.z) + bf2f((ushort)v2.z) + bf2f((ushort)v3.z);
    s[5] = bf2f((ushort)(v0.z >> 16)) + bf2f((ushort)(v1.z >> 16)) + bf2f((ushort)(v2.z >> 16)) + bf2f((ushort)(v3.z >> 16));
    s[6] = bf2f((ushort)v0.w) + bf2f((ushort)v1.w) + bf2f((ushort)v2.w) + bf2f((ushort)v3.w);
    s[7] = bf2f((ushort)(v0.w >> 16)) + bf2f((ushort)(v1.w >> 16)) + bf2f((ushort)(v2.w >> 16)) + bf2f((ushort)(v3.w >> 16));

    float4* out4 = (float4*)out;
    out4[(long)gid * 2 + 0] = make_float4(s[0], s[1], s[2], s[3]);
    out4[(long)gid * 2 + 1] = make_float4(s[4], s[5], s[6], s[7]);

    uint4 pk;
    pk.x = (uint)f2bf(s[0]) | ((uint)f2bf(s[1]) << 16);
    pk.y = (uint)f2bf(s[2]) | ((uint)f2bf(s[3]) << 16);
    pk.z = (uint)f2bf(s[4]) | ((uint)f2bf(s[5]) << 16);
    pk.w = (uint)f2bf(s[6]) | ((uint)f2bf(s[7]) << 16);
    wbf4[gid] = pk;
}

// ---------------------------------------------------------------------------
// K5 (MFMA): recon[pair][b] = sum_d w[n][d]*Un[d][b]; loss only
// ---------------------------------------------------------------------------
__global__ __launch_bounds__(256) void pass_recon_mfma(
    const float* __restrict__ h_sparse, void* __restrict__ ws,
    float* __restrict__ out)
{
    const int e = blockIdx.x >> 3, g = blockIdx.x & 7;
    const int wave = threadIdx.x >> 6, lane = threadIdx.x & 63;
    const int quad = lane >> 4, l15 = lane & 15;
    const int t = threadIdx.x;

    const int* cnt = (const int*)ws;
    const ushort* bkt = (const ushort*)((const char*)ws + BKT_B);
    const ushort* Ute = (const ushort*)((const char*)ws + UT_B) + (long)e * BB * DD;
    const ushort* wbf = (const ushort*)((const char*)ws + WBF_B);

    __shared__ float loss_blk;
    if (t == 0) loss_blk = 0.f;
    __syncthreads();

    const int c  = cnt[e];
    const int lo = (c * g) >> 3;
    const int hi = (c * (g + 1)) >> 3;

    float lsum = 0.f;

    for (int base = lo + wave * 16; base < hi; base += 64) {
        const int pidx = base + l15;
        const bool valid = pidx < hi;
        const int id = valid ? (int)bkt[e * CAP + pidx] : 0;
        const int n = id >> 2;
        const ushort* wrow = wbf + ((long)n << 9);

        f32x4 acc = {0.f, 0.f, 0.f, 0.f};

        #pragma unroll 4
        for (int kk = 0; kk < 16; ++kk) {
            const int doff = kk * 32 + quad * 8;
            const short8 afrag = *(const short8*)(wrow + doff);
            const short8 bfrag = *(const short8*)(Ute + (long)l15 * DD + doff);
            acc = __builtin_amdgcn_mfma_f32_16x16x32_bf16(afrag, bfrag, acc, 0, 0, 0);
        }

        // acc[r] = recon[pair = base + quad*4 + r][b = l15]
        #pragma unroll
        for (int r = 0; r < 4; ++r) {
            const int pr = base + quad * 4 + r;
            if (pr < hi) {
                const int id2 = (int)bkt[e * CAP + pr];
                const float h = h_sparse[(long)id2 * BB + l15];
                const float d = acc[r] - h;
                lsum += d * d;
            }
        }
    }

    #pragma unroll
    for (int off = 32; off > 0; off >>= 1) lsum += __shfl_xor(lsum, off, 64);
    if (lane == 0 && lsum != 0.f) atomicAdd(&loss_blk, lsum);
    __syncthreads();
    if (t == 0 && loss_blk != 0.f)
        atomicAdd(out + (long)NN * DD, loss_blk * (1.0f / ((float)NN * KK * BB)));
}

// ---------------------------------------------------------------------------
// Fallback path (round-1 proven) — used only if ws is too small
// ---------------------------------------------------------------------------
__global__ __launch_bounds__(256) void norm_kernel(
    const float* __restrict__ U, float* __restrict__ inv_norm,
    float* __restrict__ loss_slot)
{
    const int m = blockIdx.x;
    const int t = threadIdx.x;
    const float* Um = U + (long)m * DP1 * BB;
    float acc = 0.f;
    for (int idx = t; idx < DP1 * BB; idx += 256) {
        float v = Um[idx];
        acc += v * v;
    }
    __shared__ float s[256];
    s[t] = acc;
    __syncthreads();
    if (t < BB) {
        float tot = 0.f;
        #pragma unroll
        for (int j = 0; j < 16; ++j) tot += s[t + 16 * j];
        inv_norm[m * BB + t] = rsqrtf(tot);
    }
    if (m == 0 && t == 0) *loss_slot = 0.f;
}

__global__ __launch_bounds__(256) void dense_write_kernel(
    const float* __restrict__ h_sparse,
    const int*   __restrict__ topk,
    const float* __restrict__ U,
    const float* __restrict__ inv_norm,
    float* __restrict__ out)
{
    const int n = blockIdx.x;
    const int t = threadIdx.x;

    __shared__ float hs[KK * BB];
    __shared__ float ho[KK * BB];
    __shared__ float inv_s[KK * BB];
    __shared__ int   eidx[KK];
    __shared__ float w_s[DD];
    __shared__ float red[256];

    if (t < KK) eidx[t] = topk[n * KK + t];
    __syncthreads();
    if (t < KK * BB) {
        const int k = t / BB, b = t % BB;
        const float h  = h_sparse[(long)n * KK * BB + t];
        const float iv = inv_norm[eidx[k] * BB + b];
        ho[t]    = h;
        inv_s[t] = iv;
        hs[t]    = h * iv;
    }
    __syncthreads();

    #pragma unroll
    for (int dd = 0; dd < 2; ++dd) {
        const int d = t + dd * 256;
        float w = 0.f;
        #pragma unroll
        for (int k = 0; k < KK; ++k) {
            const float4* row = (const float4*)(U + ((long)eidx[k] * DP1 + d) * BB);
            #pragma unroll
            for (int q = 0; q < 4; ++q) {
                const float4 u4 = row[q];
                w += u4.x * hs[k * BB + 4 * q + 0];
                w += u4.y * hs[k * BB + 4 * q + 1];
                w += u4.z * hs[k * BB + 4 * q + 2];
                w += u4.w * hs[k * BB + 4 * q + 3];
            }
        }
        w_s[d] = w;
        out[(long)n * DD + d] = w;
    }
    __syncthreads();

    {
        const int pair = t & 63;
        const int k = pair >> 4, b = pair & 15;
        const int ch = t >> 6;
        const float* Ucol = U + (long)eidx[k] * DP1 * BB + b;
        float p = 0.f;
        #pragma unroll 8
        for (int d = ch * 128; d < ch * 128 + 128; ++d) {
            p += Ucol[(long)d * BB] * w_s[d];
        }
        red[t] = p;
    }
    __syncthreads();

    if (t < 64) {
        const float recon = (red[t] + red[t + 64] + red[t + 128] + red[t + 192]) * inv_s[t];
        const float diff  = recon - ho[t];
        float sq = diff * diff;
        #pragma unroll
        for (int off = 32; off > 0; off >>= 1) sq += __shfl_down(sq, off, 64);
        if (t == 0) {
            atomicAdd(out + (long)NN * DD, sq * (1.0f / ((float)NN * KK * BB)));
        }
    }
}

// ---------------------------------------------------------------------------

extern "C" void kernel_launch(void* const* d_in, const int* in_sizes, int n_in,
                              void* d_out, int out_size, void* d_ws, size_t ws_size,
                              hipStream_t stream) {
    const float* h_sparse = (const float*)d_in[0];
    const int*   topk     = (const int*)d_in[1];
    const float* U        = (const float*)d_in[2];
    float* out = (float*)d_out;

    if (ws_size >= (size_t)WS_NEED) {
        hipMemsetAsync(d_ws, 0, 256, stream);   // expert counters
        hipLaunchKernelGGL(prep_kernel, dim3(MM), dim3(256), 0, stream,
                           U, d_ws, out + (long)NN * DD);
        hipLaunchKernelGGL(build_buckets, dim3(NPAIR / 256), dim3(256), 0, stream,
                           topk, d_ws);
        hipLaunchKernelGGL(pass_writes_mfma, dim3(MM * GPE), dim3(256), 0, stream,
                           h_sparse, d_ws);
        hipLaunchKernelGGL(reduce_w, dim3(NN * DD / 8 / 256), dim3(256), 0, stream,
                           d_ws, out);
        hipLaunchKernelGGL(pass_recon_mfma, dim3(MM * GPE), dim3(256), 0, stream,
                           h_sparse, d_ws, out);
    } else {
        float* inv_norm = (float*)d_ws;
        hipLaunchKernelGGL(norm_kernel, dim3(MM), dim3(256), 0, stream,
                           U, inv_norm, out + (long)NN * DD);
        hipLaunchKernelGGL(dense_write_kernel, dim3(NN), dim3(256), 0, stream,
                           h_sparse, topk, U, inv_norm, out);
    }
}